// Round 1
// baseline (805.584 us; speedup 1.0000x reference)
//
#include <hip/hip_runtime.h>
#include <math.h>

#define N_ATOMS 2048
#define NM      512
#define KHALF   9040          // half k-grid (k=0 at index 9040 excluded; pairs f <-> 18080-f)
#define KPAD    9216          // padded, wk=0 on pads
#define TWO_PI  6.2831853071795864769f
#define SIGMA   0.5540037f
#define FOUR_PI 12.566370614359172954f

__device__ inline void inv3x3(const float* __restrict__ c, float inv[3][3], float& det) {
    float a00=c[0],a01=c[1],a02=c[2],a10=c[3],a11=c[4],a12=c[5],a20=c[6],a21=c[7],a22=c[8];
    float c00 =  a11*a22 - a12*a21;
    float c01 = -(a10*a22 - a12*a20);
    float c02 =  a10*a21 - a11*a20;
    det = a00*c00 + a01*c01 + a02*c02;
    float id = 1.0f/det;
    inv[0][0] = c00*id;
    inv[0][1] = -(a01*a22 - a02*a21)*id;
    inv[0][2] =  (a01*a12 - a02*a11)*id;
    inv[1][0] = c01*id;
    inv[1][1] =  (a00*a22 - a02*a20)*id;
    inv[1][2] = -(a00*a12 - a02*a10)*id;
    inv[2][0] = c02*id;
    inv[2][1] = -(a00*a21 - a01*a20)*id;
    inv[2][2] =  (a00*a11 - a01*a10)*id;
}

// kdata[t] = (gx, gy, gz, wk) with wk = sqrt(2*kfac); wk=0 for pads
__global__ void k_setup(const float* __restrict__ cell, float4* __restrict__ kdata) {
    int t = blockIdx.x*256 + threadIdx.x;
    if (t >= KPAD) return;
    float gx=0.f, gy=0.f, gz=0.f, wk=0.f;
    if (t < KHALF) {
        int iz = t % 41; int rem = t / 41; int iy = rem % 21; int ix = rem / 21;
        gx = (float)(ix - 10); gy = (float)(iy - 10); gz = (float)(iz - 20);
        float inv[3][3], det;
        inv3x3(cell, inv, det);
        float kx = TWO_PI*(gx*inv[0][0] + gy*inv[0][1] + gz*inv[0][2]);
        float ky = TWO_PI*(gx*inv[1][0] + gy*inv[1][1] + gz*inv[1][2]);
        float kz = TWO_PI*(gx*inv[2][0] + gy*inv[2][1] + gz*inv[2][2]);
        float k2 = kx*kx + ky*ky + kz*kz;
        float kfac = __expf(-0.5f*SIGMA*SIGMA*k2) / k2;
        wk = sqrtf(2.0f*kfac);
    }
    kdata[t] = make_float4(gx, gy, gz, wk);
}

// uq[i] = (u,v,w,q_i) fractional coords; also writes electrolyte outputs + e_corr/e_ext zeros
__global__ void atoms_prep(const float* __restrict__ pos, const float* __restrict__ q,
                           const float* __restrict__ cell, float4* __restrict__ uq,
                           float* __restrict__ out) {
    int i = blockIdx.x*256 + threadIdx.x;
    if (i < N_ATOMS) {
        float inv[3][3], det;
        inv3x3(cell, inv, det);
        float x = pos[3*i], y = pos[3*i+1], z = pos[3*i+2];
        float u = x*inv[0][0] + y*inv[1][0] + z*inv[2][0];
        float v = x*inv[0][1] + y*inv[1][1] + z*inv[2][1];
        float w = x*inv[0][2] + y*inv[1][2] + z*inv[2][2];
        float qi = q[i];
        uq[i] = make_float4(u, v, w, qi);
        if (i >= NM) out[i] = qi;
        if (i == 0) { out[N_ATOMS] = 0.f; out[N_ATOMS+1] = 0.f; }
    }
}

// Scw[k] = wk^2 * sum_{j in electrolyte} q_j cos(2*pi*g.u_j); likewise Ssw (sin)
__global__ void structf(const float4* __restrict__ kdata, const float4* __restrict__ uq,
                        float* __restrict__ Scw, float* __restrict__ Ssw) {
    int t = blockIdx.x*256 + threadIdx.x;
    if (t >= KPAD) return;
    float4 kd = kdata[t];
    float sc = 0.f, ss = 0.f;
    for (int j = NM; j < N_ATOMS; ++j) {
        float4 a = uq[j];
        float ph = TWO_PI*(kd.x*a.x + kd.y*a.y + kd.z*a.z);
        float s, c;
        __sincosf(ph, &s, &c);
        sc += a.w * c;
        ss += a.w * s;
    }
    float kfac2 = kd.w * kd.w;   // = 2*kfac (0 on pads)
    Scw[t] = kfac2 * sc;
    Ssw[t] = kfac2 * ss;
}

// Bvec[i] = -(4*pi/V) * sum_k (c_ik*Scw + s_ik*Ssw), one wave per metal atom
__global__ void __launch_bounds__(512) field_metal(const float4* __restrict__ kdata,
        const float4* __restrict__ uq, const float* __restrict__ Scw,
        const float* __restrict__ Ssw, const float* __restrict__ cell,
        float* __restrict__ Bvec) {
    int gtid = blockIdx.x*512 + threadIdx.x;
    int atom = gtid >> 6;
    int lane = threadIdx.x & 63;
    float4 a = uq[atom];
    float acc = 0.f;
    for (int k = lane; k < KPAD; k += 64) {
        float4 kd = kdata[k];
        float ph = TWO_PI*(kd.x*a.x + kd.y*a.y + kd.z*a.z);
        float s, c;
        __sincosf(ph, &s, &c);
        acc += c*Scw[k] + s*Ssw[k];
    }
    #pragma unroll
    for (int off = 32; off; off >>= 1) acc += __shfl_down(acc, off);
    if (lane == 0) {
        float inv[3][3], det;
        inv3x3(cell, inv, det);
        float V = fabsf(det);
        Bvec[atom] = -(FOUR_PI / V) * acc;
    }
}

// Split-K SYRK over lower-triangle 128x128 tiles; phases recomputed into LDS per chunk.
// partial[(t*KS+s)*16384 + r*128 + c] = per-slice unscaled A-tile contribution.
__global__ void __launch_bounds__(256, 2) syrk_tiles(const float4* __restrict__ kdata,
        const float4* __restrict__ uq, float* __restrict__ partial, int KS, int KSL) {
    int s = blockIdx.x % KS;
    int t = blockIdx.x / KS;
    int rt = 0;
    while ((rt+1)*(rt+2)/2 <= t) ++rt;
    int ct = t - rt*(rt+1)/2;
    const int row0 = rt << 7, c0 = ct << 7;
    __shared__ float crT[32][128];
    __shared__ float srT[32][128];
    __shared__ float ccT[32][128];
    __shared__ float scT[32][128];
    const int tid = threadIdx.x;
    const int i0 = (tid & 15) << 3;
    const int j0 = (tid >> 4) << 3;
    float acc[8][8];
    #pragma unroll
    for (int i = 0; i < 8; ++i)
        #pragma unroll
        for (int j = 0; j < 8; ++j) acc[i][j] = 0.f;
    const int k0 = s * KSL;
    const int nch = KSL >> 5;
    for (int ch = 0; ch < nch; ++ch) {
        int kc = k0 + (ch << 5);
        __syncthreads();
        #pragma unroll
        for (int w = 0; w < 16; ++w) {            // row phases: 128 atoms x 32 k
            int job = tid + (w << 8);
            int kk = job >> 7, a = job & 127;
            float4 kd = kdata[kc + kk];
            float4 at = uq[row0 + a];
            float ph = TWO_PI*(kd.x*at.x + kd.y*at.y + kd.z*at.z);
            float sn, cs;
            __sincosf(ph, &sn, &cs);
            crT[kk][a] = kd.w * cs;
            srT[kk][a] = kd.w * sn;
        }
        #pragma unroll
        for (int w = 0; w < 16; ++w) {            // col phases
            int job = tid + (w << 8);
            int kk = job >> 7, a = job & 127;
            float4 kd = kdata[kc + kk];
            float4 at = uq[c0 + a];
            float ph = TWO_PI*(kd.x*at.x + kd.y*at.y + kd.z*at.z);
            float sn, cs;
            __sincosf(ph, &sn, &cs);
            ccT[kk][a] = kd.w * cs;
            scT[kk][a] = kd.w * sn;
        }
        __syncthreads();
        #pragma unroll 4
        for (int kk = 0; kk < 32; ++kk) {
            float cr[8], sr[8], cc[8], sv[8];
            *(float4*)&cr[0] = *(const float4*)&crT[kk][i0];
            *(float4*)&cr[4] = *(const float4*)&crT[kk][i0+4];
            *(float4*)&sr[0] = *(const float4*)&srT[kk][i0];
            *(float4*)&sr[4] = *(const float4*)&srT[kk][i0+4];
            *(float4*)&cc[0] = *(const float4*)&ccT[kk][j0];
            *(float4*)&cc[4] = *(const float4*)&ccT[kk][j0+4];
            *(float4*)&sv[0] = *(const float4*)&scT[kk][j0];
            *(float4*)&sv[4] = *(const float4*)&scT[kk][j0+4];
            #pragma unroll
            for (int i = 0; i < 8; ++i)
                #pragma unroll
                for (int j = 0; j < 8; ++j)
                    acc[i][j] += cr[i]*cc[j] + sr[i]*sv[j];
        }
    }
    float* P = partial + ((size_t)(t*KS + s) << 14);
    #pragma unroll
    for (int i = 0; i < 8; ++i) {
        *(float4*)&P[(i0+i)*128 + j0]     = make_float4(acc[i][0], acc[i][1], acc[i][2], acc[i][3]);
        *(float4*)&P[(i0+i)*128 + j0 + 4] = make_float4(acc[i][4], acc[i][5], acc[i][6], acc[i][7]);
    }
}

// A[i][j] = A[j][i] = (4*pi/V) * sum_s partial
__global__ void reduceA(const float* __restrict__ partial, float* __restrict__ Amat,
                        const float* __restrict__ cell, int KS) {
    int idx = blockIdx.x*256 + threadIdx.x;
    if (idx >= 512*512) return;
    int i = idx >> 9, j = idx & 511;
    if (i < j) return;
    int rt = i >> 7, ct = j >> 7;
    int t = rt*(rt+1)/2 + ct;
    const float* p = partial + ((size_t)(t*KS) << 14) + ((i & 127) << 7) + (j & 127);
    float sum = 0.f;
    for (int s = 0; s < KS; ++s) sum += p[(size_t)s << 14];
    float inv[3][3], det;
    inv3x3(cell, inv, det);
    float v = (FOUR_PI / fabsf(det)) * sum;
    Amat[(size_t)i*512 + j] = v;
    Amat[(size_t)j*512 + i] = v;
}

// Cholesky panel (64 cols), rows-in-registers, rank-8 inner updates.
// Writes L back into A's lower band and its transpose rows into LT.
__global__ void __launch_bounds__(512) chol_panel(float* __restrict__ Amat,
                                                  float* __restrict__ LTm, int p) {
    const int col0 = 64*p;
    const int nr = 512 - col0;
    const int tid = threadIdx.x;
    __shared__ float pivd[8];
    __shared__ float colsm[8][8];
    __shared__ float LcB[64][8];
    float row[64];
    const bool active = tid < nr;
    const int grow = col0 + tid;
    if (active) {
        const float* ar = Amat + (size_t)grow*512 + col0;
        #pragma unroll
        for (int c = 0; c < 64; c += 4) *(float4*)&row[c] = *(const float4*)&ar[c];
    }
    #pragma unroll
    for (int jb = 0; jb < 64; jb += 8) {
        // phase A: 8 micro-steps on the 8-wide pivot block + its sub-column
        #pragma unroll
        for (int jj = 0; jj < 8; ++jj) {
            const int j = jb + jj;
            if (tid == j) pivd[jj] = row[j];
            else if (tid > j && tid < jb+8) colsm[jj][tid - jb] = row[j];
            __syncthreads();
            if (active && tid > j) {
                float inv = 1.0f / sqrtf(pivd[jj]);
                row[j] *= inv;                       // L[r][j]
                #pragma unroll
                for (int c = jj+1; c < 8; ++c)
                    row[jb+c] -= row[j] * (colsm[jj][c] * inv);
            } else if (tid == j) {
                row[j] = sqrtf(pivd[jj]);
            }
        }
        // phase B: rank-8 update of remaining panel columns
        if (active && tid >= jb+8 && tid < 64) {
            #pragma unroll
            for (int jj = 0; jj < 8; ++jj) LcB[tid][jj] = row[jb+jj];
        }
        __syncthreads();
        if (active && tid >= jb+8) {
            #pragma unroll
            for (int c = jb+8; c < 64; ++c) {
                float4 l0 = *(const float4*)&LcB[c][0];
                float4 l1 = *(const float4*)&LcB[c][4];
                row[c] -= row[jb+0]*l0.x + row[jb+1]*l0.y + row[jb+2]*l0.z + row[jb+3]*l0.w
                        + row[jb+4]*l1.x + row[jb+5]*l1.y + row[jb+6]*l1.z + row[jb+7]*l1.w;
            }
        }
        __syncthreads();
    }
    if (active) {
        float* ar = Amat + (size_t)grow*512 + col0;
        #pragma unroll
        for (int c = 0; c < 64; c += 4) *(float4*)&ar[c] = *(const float4*)&row[c];
        #pragma unroll
        for (int c = 0; c < 64; ++c)
            LTm[(size_t)(col0 + c)*512 + grow] = row[c];
    }
}

// Trailing SYRK update: A[r][c] -= sum_k L[r][col0+k]*L[c][col0+k]
__global__ void __launch_bounds__(256) chol_trail(float* __restrict__ Amat, int p) {
    const int col0 = p*64, base = col0 + 64;
    int t = blockIdx.x;
    int rt = 0;
    while ((rt+1)*(rt+2)/2 <= t) ++rt;
    int ct = t - rt*(rt+1)/2;
    const int row0 = base + rt*64, c0 = base + ct*64;
    __shared__ float LrT[64][68];
    __shared__ float LcT[64][68];
    const int tid = threadIdx.x;
    for (int idx = tid; idx < 4096; idx += 256) {
        int k = idx & 63, r = idx >> 6;
        LrT[k][r] = Amat[(size_t)(row0+r)*512 + col0 + k];
        LcT[k][r] = Amat[(size_t)(c0 +r)*512 + col0 + k];
    }
    __syncthreads();
    const int i0 = (tid & 15)*4, j0 = (tid >> 4)*4;
    float acc[4][4];
    #pragma unroll
    for (int i = 0; i < 4; ++i)
        #pragma unroll
        for (int j = 0; j < 4; ++j) acc[i][j] = 0.f;
    #pragma unroll 8
    for (int k = 0; k < 64; ++k) {
        float a[4], b[4];
        *(float4*)a = *(const float4*)&LrT[k][i0];
        *(float4*)b = *(const float4*)&LcT[k][j0];
        #pragma unroll
        for (int i = 0; i < 4; ++i)
            #pragma unroll
            for (int j = 0; j < 4; ++j) acc[i][j] += a[i]*b[j];
    }
    #pragma unroll
    for (int i = 0; i < 4; ++i) {
        float* ap = &Amat[(size_t)(row0+i0+i)*512 + c0 + j0];
        float4 v = *(float4*)ap;
        v.x -= acc[i][0]; v.y -= acc[i][1]; v.z -= acc[i][2]; v.w -= acc[i][3];
        *(float4*)ap = v;
    }
}

// Forward/back substitution for 2 RHS (B, ones) + charge-neutral combine + metal output
__global__ void __launch_bounds__(512) trsv_fin(const float* __restrict__ Amat,
        const float* __restrict__ LTm, const float* __restrict__ Bvec,
        float* __restrict__ out) {
    __shared__ float z1[512], z2[512], x1[512], x2[512];
    __shared__ float rnum[8], rden[8];
    const int tid = threadIdx.x;
    const float b1 = Bvec[tid];
    const float dinv = 1.0f / Amat[(size_t)tid*513];
    float acc1 = 0.f, acc2 = 0.f;
    float cur[8], nxt[8];
    #pragma unroll
    for (int i = 0; i < 8; ++i) cur[i] = LTm[(size_t)i*512 + tid];
    for (int jb = 0; jb < 512; jb += 8) {
        #pragma unroll
        for (int i = 0; i < 8; ++i) {
            int jn = jb + 8 + i;
            nxt[i] = (jn < 512) ? LTm[(size_t)jn*512 + tid] : 0.f;
        }
        #pragma unroll
        for (int i = 0; i < 8; ++i) {
            const int j = jb + i;
            if (tid == j) {
                z1[j] = (b1  - acc1) * dinv;
                z2[j] = (1.f - acc2) * dinv;
            }
            __syncthreads();
            const float zz1 = z1[j], zz2 = z2[j];
            if (tid > j) { acc1 += cur[i]*zz1; acc2 += cur[i]*zz2; }
        }
        #pragma unroll
        for (int i = 0; i < 8; ++i) cur[i] = nxt[i];
    }
    __syncthreads();
    acc1 = 0.f; acc2 = 0.f;
    #pragma unroll
    for (int i = 0; i < 8; ++i) cur[i] = Amat[(size_t)(511 - i)*512 + tid];
    for (int jb = 511; jb >= 7; jb -= 8) {
        #pragma unroll
        for (int i = 0; i < 8; ++i) {
            int jn = jb - 8 - i;
            nxt[i] = (jn >= 0) ? Amat[(size_t)jn*512 + tid] : 0.f;
        }
        #pragma unroll
        for (int i = 0; i < 8; ++i) {
            const int j = jb - i;
            if (tid == j) {
                x1[j] = (z1[j] - acc1) * dinv;
                x2[j] = (z2[j] - acc2) * dinv;
            }
            __syncthreads();
            const float xx1 = x1[j], xx2 = x2[j];
            if (tid < j) { acc1 += cur[i]*xx1; acc2 += cur[i]*xx2; }
        }
        #pragma unroll
        for (int i = 0; i < 8; ++i) cur[i] = nxt[i];
    }
    __syncthreads();
    float pnum = x2[tid]*b1, pden = x2[tid];
    #pragma unroll
    for (int off = 32; off; off >>= 1) {
        pnum += __shfl_down(pnum, off);
        pden += __shfl_down(pden, off);
    }
    if ((tid & 63) == 0) { rnum[tid >> 6] = pnum; rden[tid >> 6] = pden; }
    __syncthreads();
    if (tid == 0) {
        float sn = 0.f, sd = 0.f;
        #pragma unroll
        for (int i = 0; i < 8; ++i) { sn += rnum[i]; sd += rden[i]; }
        rnum[0] = sn; rden[0] = sd;
    }
    __syncthreads();
    const float ratio = rnum[0] / rden[0];
    out[tid] = x1[tid] - x2[tid]*ratio;
}

extern "C" void kernel_launch(void* const* d_in, const int* in_sizes, int n_in,
                              void* d_out, int out_size, void* d_ws, size_t ws_size,
                              hipStream_t stream) {
    (void)in_sizes; (void)n_in; (void)out_size;
    const float* pos  = (const float*)d_in[0];
    const float* q    = (const float*)d_in[1];
    const float* cell = (const float*)d_in[2];
    float* out = (float*)d_out;
    char* ws = (char*)d_ws;
    size_t off = 0;
    auto alloc = [&](size_t bytes) -> void* {
        void* p = (void*)(ws + off);
        off = (off + bytes + 255) & ~(size_t)255;
        return p;
    };
    float4* kdata = (float4*)alloc((size_t)KPAD*16);
    float4* uq    = (float4*)alloc((size_t)N_ATOMS*16);
    float*  Scw   = (float*)alloc((size_t)KPAD*4);
    float*  Ssw   = (float*)alloc((size_t)KPAD*4);
    float*  Bvec  = (float*)alloc(512*4);
    float*  Amat  = (float*)alloc((size_t)512*512*4);
    float*  LTm   = (float*)alloc((size_t)512*512*4);
    // split-K factor chosen to fit ws (deterministic for fixed ws_size)
    static const int ksopts[] = {48, 32, 24, 16, 12, 8, 6, 4, 3, 2, 1};
    int KS = 1;
    for (int ci = 0; ci < 11; ++ci) {
        size_t need = (size_t)10 * ksopts[ci] * 16384 * 4;
        if (off + need <= ws_size) { KS = ksopts[ci]; break; }
    }
    float* partial = (float*)alloc((size_t)10*KS*16384*4);
    int KSL = KPAD / KS;

    k_setup<<<dim3(KPAD/256), dim3(256), 0, stream>>>(cell, kdata);
    atoms_prep<<<dim3(N_ATOMS/256), dim3(256), 0, stream>>>(pos, q, cell, uq, out);
    structf<<<dim3(KPAD/256), dim3(256), 0, stream>>>(kdata, uq, Scw, Ssw);
    field_metal<<<dim3(64), dim3(512), 0, stream>>>(kdata, uq, Scw, Ssw, cell, Bvec);
    syrk_tiles<<<dim3(10*KS), dim3(256), 0, stream>>>(kdata, uq, partial, KS, KSL);
    reduceA<<<dim3(1024), dim3(256), 0, stream>>>(partial, Amat, cell, KS);
    for (int p = 0; p < 8; ++p) {
        chol_panel<<<dim3(1), dim3(512), 0, stream>>>(Amat, LTm, p);
        int T = 7 - p;
        if (T > 0) chol_trail<<<dim3(T*(T+1)/2), dim3(256), 0, stream>>>(Amat, p);
    }
    trsv_fin<<<dim3(1), dim3(512), 0, stream>>>(Amat, LTm, Bvec, out);
}